// Round 6
// baseline (427.014 us; speedup 1.0000x reference)
//
#include <hip/hip_runtime.h>
#include <hip/hip_bf16.h>

// Problem constants
constexpr int B  = 4;
constexpr int S  = 2048;
constexpr int H  = 1024;
constexpr int NH = 16;
constexpr int HD = 64;
constexpr int P  = 64;
constexpr int INTER = 2048;
constexpr int M  = B * S;   // 8192 rows

typedef __bf16  bf16x8   __attribute__((ext_vector_type(8)));
typedef float   floatx4  __attribute__((ext_vector_type(4)));

#define AS1 __attribute__((address_space(1)))
#define AS3 __attribute__((address_space(3)))
#define VMCNT(n) asm volatile("s_waitcnt vmcnt(" #n ")" ::: "memory")
#define LGKM0   asm volatile("s_waitcnt lgkmcnt(0)" ::: "memory")

// ---------------------------------------------------------------------------
// LayerNorm: one block per row of 1024, 256 threads, float4/thread, bf16 out
// ---------------------------------------------------------------------------
__global__ __launch_bounds__(256) void mc_ln_kernel(
    const float* __restrict__ x, const float* __restrict__ g,
    const float* __restrict__ b, __bf16* __restrict__ y)
{
    int row = blockIdx.x;
    const float4* xr = (const float4*)(x + (size_t)row * H);
    float4 v = xr[threadIdx.x];
    float s  = v.x + v.y + v.z + v.w;
    float s2 = v.x*v.x + v.y*v.y + v.z*v.z + v.w*v.w;
    #pragma unroll
    for (int off = 32; off > 0; off >>= 1) {
        s  += __shfl_down(s,  off);
        s2 += __shfl_down(s2, off);
    }
    __shared__ float ws1[4], ws2[4];
    __shared__ float smu, srv;
    int lane = threadIdx.x & 63, wid = threadIdx.x >> 6;
    if (lane == 0) { ws1[wid] = s; ws2[wid] = s2; }
    __syncthreads();
    if (threadIdx.x == 0) {
        float t1 = ws1[0] + ws1[1] + ws1[2] + ws1[3];
        float t2 = ws2[0] + ws2[1] + ws2[2] + ws2[3];
        float mu  = t1 * (1.0f / H);
        float var = t2 * (1.0f / H) - mu * mu;
        smu = mu;
        srv = rsqrtf(var + 1e-12f);
    }
    __syncthreads();
    float mu = smu, rv = srv;
    float4 gv = ((const float4*)g)[threadIdx.x];
    float4 bv = ((const float4*)b)[threadIdx.x];
    union { ushort4 u; __bf16 h[4]; } pk;
    pk.h[0] = (__bf16)((v.x - mu) * rv * gv.x + bv.x);
    pk.h[1] = (__bf16)((v.y - mu) * rv * gv.y + bv.y);
    pk.h[2] = (__bf16)((v.z - mu) * rv * gv.z + bv.z);
    pk.h[3] = (__bf16)((v.w - mu) * rv * gv.w + bv.w);
    ((ushort4*)(y + (size_t)row * H))[threadIdx.x] = pk.u;
}

// ---------------------------------------------------------------------------
// Transpose (+optional momentum update) fp32 [R][C] -> bf16 [C][R]
// ---------------------------------------------------------------------------
__global__ __launch_bounds__(256) void mc_trans_kernel(
    const float* __restrict__ src0, const float* __restrict__ mom0,
    __bf16* __restrict__ dst0,
    const float* __restrict__ src1, const float* __restrict__ mom1,
    __bf16* __restrict__ dst1,
    int Rdim, int Cdim, int do_upd)
{
    const float* src = blockIdx.z ? src1 : src0;
    const float* mom = blockIdx.z ? mom1 : mom0;
    __bf16*      dst = blockIdx.z ? dst1 : dst0;
    __shared__ float ts[32][33];
    int c0 = blockIdx.x * 32, r0 = blockIdx.y * 32;
    int tx = threadIdx.x & 31, ty0 = threadIdx.x >> 5;
    #pragma unroll
    for (int i = 0; i < 4; i++) {
        int r = ty0 + i * 8;
        size_t idx = (size_t)(r0 + r) * Cdim + c0 + tx;
        float v = src[idx];
        if (do_upd) v = 0.99f * v + 0.9f * mom[idx];
        ts[r][tx] = v;
    }
    __syncthreads();
    #pragma unroll
    for (int i = 0; i < 4; i++) {
        int r = ty0 + i * 8;
        dst[(size_t)(c0 + r) * Rdim + r0 + tx] = (__bf16)ts[tx][r];
    }
}

// fused bias updates: nb1[INTER], nb2[H]
__global__ void mc_upd_kernel(const float* __restrict__ b1, const float* __restrict__ mb1,
                              float* __restrict__ nb1,
                              const float* __restrict__ b2, const float* __restrict__ mb2,
                              float* __restrict__ nb2)
{
    int i = blockIdx.x * blockDim.x + threadIdx.x;
    if (i < INTER) nb1[i] = 0.99f * b1[i] + 0.9f * mb1[i];
    else {
        int j = i - INTER;
        if (j < H) nb2[j] = 0.99f * b2[j] + 0.9f * mb2[j];
    }
}

// ---------------------------------------------------------------------------
// m201-style 8-phase bf16 MFMA GEMM: C[M,N]=A[M,K]@Bt[N,K]^T (+bias/res/relu)
//
// BM=BN=256, BK=64, 512 thr = 8 waves (2M x 4N), wave tile 128x64,
// 16x16x32 MFMA. Grid = (N/256)*(M/256), 1D, XCD-swizzled.
//
// Per K-tile: 4 phases = C-quadrants (m0n0, m0n1, m1n1, m1n0); reads/phase =
// 12/4/8/0 ds_read_b128 (ar, brA, brB register-cached across quadrants).
// Phase = { reads | stage 1 half-tile (2 gload_lds) | barrier | lgkmcnt(0) |
// setprio(1) 16xMFMA setprio(0) | barrier }.  vmcnt(6) ONLY at P4.
//
// Staging ledger (race-checked): half-tiles q ordered [A0,B0,A1,B1] per tile;
// prologue issues q=0..6, vmcnt(6) (=> tile0 landed). Phase p of tile t issues
// q=4t+6+p (reaches tile t+2, buf t&1 — safe: that half's last LDS read
// retired >=1 phase-barrier earlier via per-phase lgkmcnt(0)+end-barrier).
// P4 gate: vmcnt(6) => tile t+1 fully landed (in-order retirement);
// t==NT-2 -> vmcnt(0); t==NT-1 -> none.
//
// LDS per buffer: A[256][64], B[256][64]; elem off(row,c4)=row*64+(c4^(row&7))*8;
// linear gload_lds dest + inverse-swizzled global source (cg=(lane&7)^(lane>>3),
// valid since staged row%8 == lane>>3). Frag reads apply the same XOR —
// measured 0 bank conflicts in R4/R5 with this exact form.
// ---------------------------------------------------------------------------
__global__ __launch_bounds__(512, 2) void mc_gemm8(
    const __bf16* __restrict__ A, const __bf16* __restrict__ Bt,
    const float* __restrict__ bias,
    const float* __restrict__ resF, const __bf16* __restrict__ resB,
    float* __restrict__ outF, __bf16* __restrict__ outB,
    int Ndim, int Kdim, int do_relu)
{
    constexpr int ABUF = 256 * 64;         // elems per A buffer (32 KB)
    constexpr int BBUF = 256 * 64;
    __shared__ alignas(128) __bf16 lds[2 * ABUF + 2 * BBUF];   // 128 KB

    int tid  = threadIdx.x;
    int lane = tid & 63;
    int w    = tid >> 6;
    int wm   = w >> 2;                     // 0..1
    int wn   = w & 3;                      // 0..3
    int l16  = lane & 15;
    int quad = lane >> 4;
    int l3   = lane >> 3;
    int l7   = lane & 7;
    int cg   = l7 ^ l3;                    // inverse-swizzled source chunk

    // XCD-aware bijective swizzle (nwg divisible by 8: 128 or 256)
    int NBX  = Ndim >> 8;
    int cpx  = gridDim.x >> 3;
    int gid  = blockIdx.x;
    int wgid = (gid & 7) * cpx + (gid >> 3);
    int bx   = wgid % NBX, by = wgid / NBX;
    int m0   = by * 256,   n0 = bx * 256;

    const int NT = Kdim >> 6;              // K-tiles of 64 (>= 16 here)

    // --- staging precompute (A halves: rows ah*64+{0..63} U {128+ah*64+..}) ---
    int rA0 = w * 8 + l3;                  // l=0 row-part
    int rA1 = 128 + rA0;                   // l=1
    const __bf16* aP0 = A + (size_t)(m0 + rA0) * Kdim + cg * 8;
    const __bf16* aP1 = A + (size_t)(m0 + rA1) * Kdim + cg * 8;
    int aD0 = rA0 * 64 + l7 * 8;
    int aD1 = rA1 * 64 + l7 * 8;
    // B halves: rows g*64 + bh*32 + r32
    int rr0 = w * 8 + l3, rr1 = 64 + rr0;
    int rB0 = (rr0 >> 5) * 64 + (rr0 & 31);
    int rB1 = (rr1 >> 5) * 64 + (rr1 & 31);
    const __bf16* bP0 = Bt + (size_t)(n0 + rB0) * Kdim + cg * 8;
    const __bf16* bP1 = Bt + (size_t)(n0 + rB1) * Kdim + cg * 8;
    int bD0 = rB0 * 64 + l7 * 8;
    int bD1 = rB1 * 64 + l7 * 8;
    size_t K64 = (size_t)Kdim * 64;        // A half row-block advance
    size_t K32 = (size_t)Kdim * 32;        // B half row-block advance

    auto issueHalf = [&](int q) {
        if (q >= 4 * NT) return;
        int tq = q >> 2, hh = q & 3, buf = tq & 1;
        int k0 = tq << 6;
        if ((hh & 1) == 0) {               // A half (hh=0 -> ah0, hh=2 -> ah1)
            int ah = hh >> 1;
            __builtin_amdgcn_global_load_lds(
                (const AS1 void*)(aP0 + (size_t)ah * K64 + k0),
                (AS3 void*)(lds + buf * ABUF + ah * 4096 + aD0), 16, 0, 0);
            __builtin_amdgcn_global_load_lds(
                (const AS1 void*)(aP1 + (size_t)ah * K64 + k0),
                (AS3 void*)(lds + buf * ABUF + ah * 4096 + aD1), 16, 0, 0);
        } else {                           // B half (hh=1 -> bh0, hh=3 -> bh1)
            int bh = hh >> 1;
            __builtin_amdgcn_global_load_lds(
                (const AS1 void*)(bP0 + (size_t)bh * K32 + k0),
                (AS3 void*)(lds + 2 * ABUF + buf * BBUF + bh * 2048 + bD0), 16, 0, 0);
            __builtin_amdgcn_global_load_lds(
                (const AS1 void*)(bP1 + (size_t)bh * K32 + k0),
                (AS3 void*)(lds + 2 * ABUF + buf * BBUF + bh * 2048 + bD1), 16, 0, 0);
        }
    };

    // --- fragment offsets (kk=0; kk=1 is ^32) ---
    int aoff[8], boff[4];
    #pragma unroll
    for (int i = 0; i < 8; i++) {
        int row = wm * 128 + i * 16 + l16;
        aoff[i] = row * 64 + ((quad ^ (row & 7)) * 8);
    }
    #pragma unroll
    for (int j = 0; j < 4; j++) {
        int row = wn * 64 + j * 16 + l16;
        boff[j] = row * 64 + ((quad ^ (row & 7)) * 8);
    }

    // --- prologue: 7 half-tiles (tile0 full + tile1 A0,B0,A1), gate tile0 ---
    #pragma unroll
    for (int q = 0; q < 7; q++) issueHalf(q);
    VMCNT(6);
    __builtin_amdgcn_sched_barrier(0);
    __builtin_amdgcn_s_barrier();
    __builtin_amdgcn_sched_barrier(0);

    floatx4 acc[8][4] = {};

    for (int t = 0; t < NT; t++) {
        const __bf16* Ab = lds + (t & 1) * ABUF;
        const __bf16* Bb = lds + 2 * ABUF + (t & 1) * BBUF;
        bf16x8 ar[4][2], brA[2][2], brB[2][2];

        // ===== P1: quadrant (m0,n0) — reads ar(mh0) + brA(nh0) =====
        #pragma unroll
        for (int i = 0; i < 4; i++) {
            ar[i][0] = *(const bf16x8*)&Ab[aoff[i]];
            ar[i][1] = *(const bf16x8*)&Ab[aoff[i] ^ 32];
        }
        #pragma unroll
        for (int j = 0; j < 2; j++) {
            brA[j][0] = *(const bf16x8*)&Bb[boff[j]];
            brA[j][1] = *(const bf16x8*)&Bb[boff[j] ^ 32];
        }
        issueHalf(4 * t + 7);
        __builtin_amdgcn_sched_barrier(0);
        __builtin_amdgcn_s_barrier();
        LGKM0; __builtin_amdgcn_sched_barrier(0);
        __builtin_amdgcn_s_setprio(1);
        #pragma unroll
        for (int i = 0; i < 4; i++)
            #pragma unroll
            for (int j = 0; j < 2; j++)
                #pragma unroll
                for (int kk = 0; kk < 2; kk++)
                    acc[i][j] = __builtin_amdgcn_mfma_f32_16x16x32_bf16(
                        ar[i][kk], brA[j][kk], acc[i][j], 0, 0, 0);
        __builtin_amdgcn_s_setprio(0);
        __builtin_amdgcn_sched_barrier(0);
        __builtin_amdgcn_s_barrier();

        // ===== P2: quadrant (m0,n1) — reads brB(nh1) =====
        #pragma unroll
        for (int j = 0; j < 2; j++) {
            brB[j][0] = *(const bf16x8*)&Bb[boff[2 + j]];
            brB[j][1] = *(const bf16x8*)&Bb[boff[2 + j] ^ 32];
        }
        issueHalf(4 * t + 8);
        __builtin_amdgcn_sched_barrier(0);
        __builtin_amdgcn_s_barrier();
        LGKM0; __builtin_amdgcn_sched_barrier(0);
        __builtin_amdgcn_s_setprio(1);
        #pragma unroll
        for (int i = 0; i < 4; i++)
            #pragma unroll
            for (int j = 0; j < 2; j++)
                #pragma unroll
                for (int kk = 0; kk < 2; kk++)
                    acc[i][2 + j] = __builtin_amdgcn_mfma_f32_16x16x32_bf16(
                        ar[i][kk], brB[j][kk], acc[i][2 + j], 0, 0, 0);
        __builtin_amdgcn_s_setprio(0);
        __builtin_amdgcn_sched_barrier(0);
        __builtin_amdgcn_s_barrier();

        // ===== P3: quadrant (m1,n1) — reads ar(mh1), brB cached =====
        #pragma unroll
        for (int i = 0; i < 4; i++) {
            ar[i][0] = *(const bf16x8*)&Ab[aoff[4 + i]];
            ar[i][1] = *(const bf16x8*)&Ab[aoff[4 + i] ^ 32];
        }
        issueHalf(4 * t + 9);
        __builtin_amdgcn_sched_barrier(0);
        __builtin_amdgcn_s_barrier();
        LGKM0; __builtin_amdgcn_sched_barrier(0);
        __builtin_amdgcn_s_setprio(1);
        #pragma unroll
        for (int i = 0; i < 4; i++)
            #pragma unroll
            for (int j = 0; j < 2; j++)
                #pragma unroll
                for (int kk = 0; kk < 2; kk++)
                    acc[4 + i][2 + j] = __builtin_amdgcn_mfma_f32_16x16x32_bf16(
                        ar[i][kk], brB[j][kk], acc[4 + i][2 + j], 0, 0, 0);
        __builtin_amdgcn_s_setprio(0);
        __builtin_amdgcn_sched_barrier(0);
        __builtin_amdgcn_s_barrier();

        // ===== P4: quadrant (m1,n0) — no reads (ar, brA cached); GATE =====
        issueHalf(4 * t + 10);
        if (t + 2 < NT)       { VMCNT(6); }
        else if (t + 2 == NT) { VMCNT(0); }
        __builtin_amdgcn_sched_barrier(0);
        __builtin_amdgcn_s_barrier();
        __builtin_amdgcn_sched_barrier(0);
        __builtin_amdgcn_s_setprio(1);
        #pragma unroll
        for (int i = 0; i < 4; i++)
            #pragma unroll
            for (int j = 0; j < 2; j++)
                #pragma unroll
                for (int kk = 0; kk < 2; kk++)
                    acc[4 + i][j] = __builtin_amdgcn_mfma_f32_16x16x32_bf16(
                        ar[i][kk], brA[j][kk], acc[4 + i][j], 0, 0, 0);
        __builtin_amdgcn_s_setprio(0);
        __builtin_amdgcn_sched_barrier(0);
        __builtin_amdgcn_s_barrier();
    }

    // epilogue: col = l16 side, row = quad*4 + reg (16x16x32 C/D mapping)
    #pragma unroll
    for (int i = 0; i < 8; i++) {
        #pragma unroll
        for (int j = 0; j < 4; j++) {
            int col = n0 + wn * 64 + j * 16 + l16;
            float bv = bias ? bias[col] : 0.0f;
            #pragma unroll
            for (int r = 0; r < 4; r++) {
                int row = m0 + wm * 128 + i * 16 + quad * 4 + r;
                size_t idx = (size_t)row * Ndim + col;
                float v = acc[i][j][r] + bv;
                if (resF)    v += resF[idx];
                if (resB)    v += (float)resB[idx];
                if (do_relu) v  = fmaxf(v, 0.0f);
                if (outF) outF[idx] = v;
                if (outB) outB[idx] = (__bf16)v;
            }
        }
    }
}

// ---------------------------------------------------------------------------
// Fused q-projection + persistent attention (verified).
// Block = 128 rows x 2 heads.
// ---------------------------------------------------------------------------
constexpr int QLD = 136;
constexpr int KLD = 72;

__global__ __launch_bounds__(256) void mc_qattn(
    const __bf16* __restrict__ A,      // normb [M,H]
    const __bf16* __restrict__ Bt,     // Wqt [H,H]
    const float* __restrict__ bq,
    const float* __restrict__ pv,
    __bf16* __restrict__ attn)
{
    __shared__ __bf16 Qs[128 * QLD];
    __shared__ union {
        struct { __bf16 As[128 * 64]; __bf16 Bs[128 * 64]; } g;
        struct { __bf16 Ks[64 * KLD]; __bf16 KTs[64 * KLD];
                 __bf16 Ps[128 * KLD]; } a;
    } u;

    int tid  = threadIdx.x;
    int lane = tid & 63;
    int w    = tid >> 6;
    int l16  = lane & 15;
    int quad = lane >> 4;
    int sw   = l16 & 7;

    int hp = blockIdx.x;
    int m0 = blockIdx.y * 128;
    int n0 = hp * 128;

    int wm = (w >> 1) * 64, wn = (w & 1) * 64;
    floatx4 acc[4][4] = {};
    for (int k0 = 0; k0 < H; k0 += 64) {
        #pragma unroll
        for (int t = 0; t < 4; t++) {
            int f = t * 256 + tid;
            int r = f >> 3, c = (f & 7) ^ (r & 7);
            __builtin_amdgcn_global_load_lds(
                (const AS1 void*)(A + (size_t)(m0 + r) * H + k0 + c * 8),
                (AS3 void*)(u.g.As + f * 8), 16, 0, 0);
        }
        #pragma unroll
        for (int t = 0; t < 4; t++) {
            int f = t * 256 + tid;
            int r = f >> 3, c = (f & 7) ^ (r & 7);
            __builtin_amdgcn_global_load_lds(
                (const AS1 void*)(Bt + (size_t)(n0 + r) * H + k0 + c * 8),
                (AS3 void*)(u.g.Bs + f * 8), 16, 0, 0);
        }
        __syncthreads();
        #pragma unroll
        for (int ks = 0; ks < 2; ks++) {
            int cq = ((ks << 2) | quad) ^ sw;
            bf16x8 af[4], bfr[4];
            #pragma unroll
            for (int i = 0; i < 4; i++)
                af[i] = *(const bf16x8*)&u.g.As[(wm + i * 16 + l16) * 64 + cq * 8];
            #pragma unroll
            for (int j = 0; j < 4; j++)
                bfr[j] = *(const bf16x8*)&u.g.Bs[(wn + j * 16 + l16) * 64 + cq * 8];
            #pragma unroll
            for (int i = 0; i < 4; i++)
                #pragma unroll
                for (int j = 0; j < 4; j++)
                    acc[i][j] = __builtin_amdgcn_mfma_f32_16x16x32_bf16(
                        af[i], bfr[j], acc[i][j], 0, 0, 0);
        }
        __syncthreads();
    }

    #pragma unroll
    for (int i = 0; i < 4; i++) {
        #pragma unroll
        for (int j = 0; j < 4; j++) {
            int col = wn + j * 16 + l16;
            float bv = bq[n0 + col];
            #pragma unroll
            for (int r = 0; r < 4; r++) {
                int row = wm + i * 16 + quad * 4 + r;
                Qs[row * QLD + col] = (__bf16)(acc[i][j][r] + bv);
            }
        }
    }

    int rbase = w * 32;
    #pragma unroll
    for (int hh = 0; hh < 2; hh++) {
        int gh = 2 * hp + hh;
        __syncthreads();
        for (int i = tid; i < 64 * 64; i += 256) {
            int p = i >> 6, d = i & 63;
            __bf16 bv = (__bf16)pv[(size_t)p * H + gh * 64 + d];
            u.a.Ks[p * KLD + d]  = bv;
            u.a.KTs[d * KLD + p] = bv;
        }
        __syncthreads();

        floatx4 sc[2][4] = {};
        #pragma unroll
        for (int ks = 0; ks < 2; ks++) {
            bf16x8 aq[2], bk[4];
            #pragma unroll
            for (int i = 0; i < 2; i++)
                aq[i] = *(const bf16x8*)&Qs[(rbase + i * 16 + l16) * QLD +
                                            hh * 64 + ks * 32 + quad * 8];
            #pragma unroll
            for (int j = 0; j < 4; j++)
                bk[j] = *(const bf16x8*)&u.a.Ks[(j * 16 + l16) * KLD + ks * 32 + quad * 8];
            #pragma unroll
            for (int i = 0; i < 2; i++)
                #pragma unroll
                for (int j = 0; j < 4; j++)
                    sc[i][j] = __builtin_amdgcn_mfma_f32_16x16x32_bf16(
                        aq[i], bk[j], sc[i][j], 0, 0, 0);
        }

        #pragma unroll
        for (int i = 0; i < 2; i++) {
            #pragma unroll
            for (int r = 0; r < 4; r++) {
                float v0 = sc[i][0][r] * 0.125f;
                float v1 = sc[i][1][r] * 0.125f;
                float v2 = sc[i][2][r] * 0.125f;
                float v3 = sc[i][3][r] * 0.125f;
                float mx = fmaxf(fmaxf(v0, v1), fmaxf(v2, v3));
                #pragma unroll
                for (int off = 8; off > 0; off >>= 1) mx = fmaxf(mx, __shfl_xor(mx, off));
                float e0 = __expf(v0 - mx), e1 = __expf(v1 - mx);
                float e2 = __expf(v2 - mx), e3 = __expf(v3 - mx);
                float sm = e0 + e1 + e2 + e3;
                #pragma unroll
                for (int off = 8; off > 0; off >>= 1) sm += __shfl_xor(sm, off);
                float inv = __frcp_rn(sm);
                int row = rbase + i * 16 + quad * 4 + r;
                u.a.Ps[row * KLD +  0 + l16] = (__bf16)(e0 * inv);
                u.a.Ps[row * KLD + 16 + l16] = (__bf16)(e1 * inv);
                u.a.Ps[row * KLD + 32 + l16] = (__bf16)(e2 * inv);
                u.a.Ps[row * KLD + 48 + l16] = (__bf16)(e3 * inv);
            }
        }
        __syncthreads();

        floatx4 ov[2][4] = {};
        #pragma unroll
        for (int ks = 0; ks < 2; ks++) {
            bf16x8 ap[2], bkt[4];
            #pragma unroll
            for (int i = 0; i < 2; i++)
                ap[i] = *(const bf16x8*)&u.a.Ps[(rbase + i * 16 + l16) * KLD + ks * 32 + quad * 8];
            #pragma unroll
            for (int j = 0; j < 4; j++)
                bkt[j] = *(const bf16x8*)&u.a.KTs[(j * 16 + l16) * KLD + ks * 32 + quad * 8];
            #pragma unroll
            for (int i = 0; i < 2; i++)
                #pragma unroll
                for (int j = 0; j < 4; j++)
                    ov[i][j] = __builtin_amdgcn_mfma_f32_16x16x32_bf16(
                        ap[i], bkt[j], ov[i][j], 0, 0, 0);
        }

        #pragma unroll
        for (int i = 0; i < 2; i++) {
            #pragma unroll
            for (int j = 0; j < 4; j++) {
                int col = j * 16 + l16;
                #pragma unroll
                for (int r = 0; r < 4; r++) {
                    int row = rbase + i * 16 + quad * 4 + r;
                    attn[(size_t)(m0 + row) * H + gh * 64 + col] = (__bf16)ov[i][j][r];
                }
            }
        }
    }
}

// ---------------------------------------------------------------------------
extern "C" void kernel_launch(void* const* d_in, const int* in_sizes, int n_in,
                              void* d_out, int out_size, void* d_ws, size_t ws_size,
                              hipStream_t stream)
{
    const float* hidden = (const float*)d_in[0];
    const float* pv   = (const float*)d_in[3];
    const float* Wq   = (const float*)d_in[4];
    const float* bq   = (const float*)d_in[5];
    const float* Wo   = (const float*)d_in[6];
    const float* bo   = (const float*)d_in[7];
    const float* ln_g = (const float*)d_in[8];
    const float* ln_b = (const float*)d_in[9];
    const float* W1   = (const float*)d_in[10];
    const float* b1   = (const float*)d_in[11];
    const float* W2   = (const float*)d_in[12];
    const float* b2   = (const float*)d_in[13];
    const float* mW1  = (const float*)d_in[14];
    const float* mb1  = (const float*)d_in[15];
    const float* mW2  = (const float*)d_in[16];
    const float* mb2  = (const float*)d_in[17];

    float* out = (float*)d_out;
    char*  wsb = (char*)d_ws;

    constexpr size_t MB = 1024 * 1024;
    __bf16* normb  = (__bf16*)(wsb);               // 16 MB  [M,H]
    __bf16* attnb  = (__bf16*)(wsb + 16  * MB);    // 16 MB  [M,H]
    __bf16* out1b  = (__bf16*)(wsb + 32  * MB);    // 16 MB  [M,H]
    __bf16* hb     = (__bf16*)(wsb + 48  * MB);    // 32 MB  [M,INTER]
    __bf16* Wqt    = (__bf16*)(wsb + 80  * MB);    // 2 MB   [H,H]
    __bf16* Wot    = (__bf16*)(wsb + 82  * MB);    // 2 MB   [H,H]
    __bf16* W1t    = (__bf16*)(wsb + 84  * MB);    // 4 MB   [INTER,H]
    __bf16* W2t    = (__bf16*)(wsb + 88  * MB);    // 4 MB   [H,INTER]
    float*  nb1    = (float*) (wsb + 92  * MB);    // 8 KB
    float*  nb2    = (float*) (wsb + 92  * MB + 8192);

    // weight prep
    mc_trans_kernel<<<dim3(32, 32, 2), 256, 0, stream>>>(
        Wq, nullptr, Wqt, Wo, nullptr, Wot, H, H, 0);
    mc_trans_kernel<<<dim3(64, 32, 1), 256, 0, stream>>>(
        W1, mW1, W1t, nullptr, nullptr, nullptr, H, INTER, 1);
    mc_trans_kernel<<<dim3(32, 64, 1), 256, 0, stream>>>(
        W2, mW2, W2t, nullptr, nullptr, nullptr, INTER, H, 1);
    mc_upd_kernel<<<(INTER + H + 255) / 256, 256, 0, stream>>>(b1, mb1, nb1, b2, mb2, nb2);

    // 1) hs_norm = LN(hidden) -> bf16
    mc_ln_kernel<<<M, 256, 0, stream>>>(hidden, ln_g, ln_b, normb);

    // 2+3) fused q-projection + attention -> attnb
    mc_qattn<<<dim3(NH / 2, M / 128), 256, 0, stream>>>(normb, Wqt, bq, pv, attnb);

    // 4) out1 = hidden + attnb @ Wo + bo -> bf16 out1b  (N=1024,K=1024; 128 wg)
    mc_gemm8<<<(H / 256) * (M / 256), 512, 0, stream>>>(
        attnb, Wot, bo, hidden, nullptr, nullptr, out1b, H, H, 0);

    // 5) h = relu(out1b @ W1t^T + nb1) -> bf16          (N=2048,K=1024; 256 wg)
    mc_gemm8<<<(INTER / 256) * (M / 256), 512, 0, stream>>>(
        out1b, W1t, nb1, nullptr, nullptr, nullptr, hb, INTER, H, 1);

    // 6) out = out1b + hb @ W2t^T + nb2 -> fp32 d_out   (N=1024,K=2048; 128 wg)
    mc_gemm8<<<(H / 256) * (M / 256), 512, 0, stream>>>(
        hb, W2t, nb2, nullptr, out1b, out, nullptr, H, INTER, 0);
}

// Round 7
// 369.543 us; speedup vs baseline: 1.1555x; 1.1555x over previous
//
#include <hip/hip_runtime.h>
#include <hip/hip_bf16.h>

// Problem constants
constexpr int B  = 4;
constexpr int S  = 2048;
constexpr int H  = 1024;
constexpr int NH = 16;
constexpr int HD = 64;
constexpr int P  = 64;
constexpr int INTER = 2048;
constexpr int M  = B * S;   // 8192 rows

typedef __bf16  bf16x8   __attribute__((ext_vector_type(8)));
typedef float   floatx4  __attribute__((ext_vector_type(4)));

#define AS1 __attribute__((address_space(1)))
#define AS3 __attribute__((address_space(3)))
#define VMCNT(n) asm volatile("s_waitcnt vmcnt(" #n ")" ::: "memory")

// ---------------------------------------------------------------------------
// LayerNorm: one block per row of 1024, 256 threads, float4/thread, bf16 out
// ---------------------------------------------------------------------------
__global__ __launch_bounds__(256) void mc_ln_kernel(
    const float* __restrict__ x, const float* __restrict__ g,
    const float* __restrict__ b, __bf16* __restrict__ y)
{
    int row = blockIdx.x;
    const float4* xr = (const float4*)(x + (size_t)row * H);
    float4 v = xr[threadIdx.x];
    float s  = v.x + v.y + v.z + v.w;
    float s2 = v.x*v.x + v.y*v.y + v.z*v.z + v.w*v.w;
    #pragma unroll
    for (int off = 32; off > 0; off >>= 1) {
        s  += __shfl_down(s,  off);
        s2 += __shfl_down(s2, off);
    }
    __shared__ float ws1[4], ws2[4];
    __shared__ float smu, srv;
    int lane = threadIdx.x & 63, wid = threadIdx.x >> 6;
    if (lane == 0) { ws1[wid] = s; ws2[wid] = s2; }
    __syncthreads();
    if (threadIdx.x == 0) {
        float t1 = ws1[0] + ws1[1] + ws1[2] + ws1[3];
        float t2 = ws2[0] + ws2[1] + ws2[2] + ws2[3];
        float mu  = t1 * (1.0f / H);
        float var = t2 * (1.0f / H) - mu * mu;
        smu = mu;
        srv = rsqrtf(var + 1e-12f);
    }
    __syncthreads();
    float mu = smu, rv = srv;
    float4 gv = ((const float4*)g)[threadIdx.x];
    float4 bv = ((const float4*)b)[threadIdx.x];
    union { ushort4 u; __bf16 h[4]; } pk;
    pk.h[0] = (__bf16)((v.x - mu) * rv * gv.x + bv.x);
    pk.h[1] = (__bf16)((v.y - mu) * rv * gv.y + bv.y);
    pk.h[2] = (__bf16)((v.z - mu) * rv * gv.z + bv.z);
    pk.h[3] = (__bf16)((v.w - mu) * rv * gv.w + bv.w);
    ((ushort4*)(y + (size_t)row * H))[threadIdx.x] = pk.u;
}

// ---------------------------------------------------------------------------
// Fused weight prep: 4 transposes (+momentum) + bias updates in ONE launch.
// Blocks 0..1023: Wq^T; 1024..2047: Wo^T; 2048..4095: W1^T(+mom);
// 4096..6143: W2^T(+mom); 6144..6155: bias updates.
// ---------------------------------------------------------------------------
__global__ __launch_bounds__(256) void mc_prep(
    const float* __restrict__ Wq, const float* __restrict__ Wo,
    const float* __restrict__ W1, const float* __restrict__ mW1,
    const float* __restrict__ W2, const float* __restrict__ mW2,
    __bf16* __restrict__ Wqt, __bf16* __restrict__ Wot,
    __bf16* __restrict__ W1t, __bf16* __restrict__ W2t,
    const float* __restrict__ b1, const float* __restrict__ mb1, float* __restrict__ nb1,
    const float* __restrict__ b2, const float* __restrict__ mb2, float* __restrict__ nb2)
{
    __shared__ float ts[32][33];
    int idx = blockIdx.x;
    if (idx >= 6144) {
        int i = (idx - 6144) * 256 + threadIdx.x;   // [0, 3072)
        if (i < INTER) nb1[i] = 0.99f * b1[i] + 0.9f * mb1[i];
        else {
            int j = i - INTER;
            if (j < H) nb2[j] = 0.99f * b2[j] + 0.9f * mb2[j];
        }
        return;
    }
    const float* src; const float* mom = nullptr; __bf16* dst;
    int bx, by, Rdim, Cdim; int upd = 0;
    if (idx < 1024)      { src = Wq; dst = Wqt; bx = idx & 31; by = idx >> 5; Rdim = H; Cdim = H; }
    else if (idx < 2048) { int i = idx - 1024; src = Wo; dst = Wot; bx = i & 31; by = i >> 5; Rdim = H; Cdim = H; }
    else if (idx < 4096) { int i = idx - 2048; src = W1; mom = mW1; dst = W1t; bx = i & 63; by = i >> 6; Rdim = H; Cdim = INTER; upd = 1; }
    else                 { int i = idx - 4096; src = W2; mom = mW2; dst = W2t; bx = i & 31; by = i >> 5; Rdim = INTER; Cdim = H; upd = 1; }
    int c0 = bx * 32, r0 = by * 32;
    int tx = threadIdx.x & 31, ty0 = threadIdx.x >> 5;
    #pragma unroll
    for (int i = 0; i < 4; i++) {
        int r = ty0 + i * 8;
        size_t id = (size_t)(r0 + r) * Cdim + c0 + tx;
        float v = src[id];
        if (upd) v = 0.99f * v + 0.9f * mom[id];
        ts[r][tx] = v;
    }
    __syncthreads();
    #pragma unroll
    for (int i = 0; i < 4; i++) {
        int r = ty0 + i * 8;
        dst[(size_t)(c0 + r) * Rdim + r0 + tx] = (__bf16)ts[tx][r];
    }
}

// ---------------------------------------------------------------------------
// Co-resident pipelined bf16 MFMA GEMM: C = A[M,K] @ Bt[N,K]^T (+bias/res/relu)
//
// Round-7 geometry: BM=BN=128, BK=32, 256 threads = 4 waves (2Mx2N),
// wave tile 64x64 (FM=4, FN=4), 16x16x32 MFMA. LDS = 3 slots x (4KB A + 4KB B)
// x2B = 48KB -> 3 blocks/CU resource limit; grids 512/1024 blocks -> 2-3
// blocks RESIDENT per CU. Cross-block overlap replaces intra-block pipelining:
// while one block sits at its gate/barrier, co-resident blocks' waves issue
// MFMA/LDS on the same SIMDs (m114 mechanism; R3-R6 all ran 1 block/CU and
// were barrier-lockstep-bound).
//
// Ledger (LPT=4 loads/tile: A2+B2; distance D=2, slots 3):
//   prologue: stage tiles 0,1 (8 loads); VMCNT(4) => tile0 landed; barrier.
//   iter t: gate (t>=1): VMCNT(t+1<NT ? 4 : 0) => tile t landed; barrier.
//     phase A: stageA(t+2) | read br[4], ar[0..2) | 8 MFMA
//     phase B: stageB(t+2) | read ar[2..4)        | 8 MFMA
//   stage(t+2) targets slot (t+2)%3 == (t-1)%3, issued after gate-barrier of
//   t which waves pass only after their tile-(t-1) frag reads retired (each
//   read has a dependent MFMA before that barrier) -> race-free.
//
// LDS layout per slot (R3/R4-verified, 0 bank conflicts): elem
// off(row,c4) = row*32 + (c4 ^ ((row>>1)&3))*8; linear gload_lds dest +
// inverse-swizzled global source; frag reads apply the same XOR.
// ---------------------------------------------------------------------------
__global__ __launch_bounds__(256, 3) void mc_gemm_t(
    const __bf16* __restrict__ A, const __bf16* __restrict__ Bt,
    const float* __restrict__ bias,
    const float* __restrict__ resF, const __bf16* __restrict__ resB,
    float* __restrict__ outF, __bf16* __restrict__ outB,
    int Ndim, int Kdim, int do_relu)
{
    constexpr int ASLOT = 128 * 32;        // 4096 elems = 8 KB
    __shared__ alignas(128) __bf16 lds[6 * ASLOT];   // 3 A slots + 3 B slots

    int tid  = threadIdx.x;
    int lane = tid & 63;
    int w    = tid >> 6;                   // 0..3
    int wm   = w >> 1;                     // 0..1
    int wn   = w & 1;                      // 0..1
    int l16  = lane & 15;
    int quad = lane >> 4;

    // XCD-aware bijective swizzle (grid = 512 or 1024, both %8==0)
    int NBX  = Ndim >> 7;
    int cpx  = gridDim.x >> 3;
    int gid  = blockIdx.x;
    int wgid = (gid & 7) * cpx + (gid >> 3);
    int bx   = wgid % NBX, by = wgid / NBX;
    int m0   = by * 128,   n0 = bx * 128;

    const int NT = Kdim >> 5;              // K-tiles of 32

    // staging sources (inverse-swizzled global addresses)
    int f0 = tid, f1 = 256 + tid;
    int r0s = f0 >> 2, c0s = (f0 & 3) ^ ((r0s >> 1) & 3);
    int r1s = f1 >> 2, c1s = (f1 & 3) ^ ((r1s >> 1) & 3);
    const __bf16* aS0 = A  + (size_t)(m0 + r0s) * Kdim + c0s * 8;
    const __bf16* aS1 = A  + (size_t)(m0 + r1s) * Kdim + c1s * 8;
    const __bf16* bS0 = Bt + (size_t)(n0 + r0s) * Kdim + c0s * 8;
    const __bf16* bS1 = Bt + (size_t)(n0 + r1s) * Kdim + c1s * 8;

    auto stageA = [&](int t) {
        int k0 = t * 32, s = t % 3;
        __builtin_amdgcn_global_load_lds((const AS1 void*)(aS0 + k0),
            (AS3 void*)(lds + s * ASLOT + f0 * 8), 16, 0, 0);
        __builtin_amdgcn_global_load_lds((const AS1 void*)(aS1 + k0),
            (AS3 void*)(lds + s * ASLOT + f1 * 8), 16, 0, 0);
    };
    auto stageB = [&](int t) {
        int k0 = t * 32, s = t % 3;
        __builtin_amdgcn_global_load_lds((const AS1 void*)(bS0 + k0),
            (AS3 void*)(lds + 3 * ASLOT + s * ASLOT + f0 * 8), 16, 0, 0);
        __builtin_amdgcn_global_load_lds((const AS1 void*)(bS1 + k0),
            (AS3 void*)(lds + 3 * ASLOT + s * ASLOT + f1 * 8), 16, 0, 0);
    };

    // loop-invariant fragment offsets (elements)
    int aoff[4], boff[4];
    #pragma unroll
    for (int i = 0; i < 4; i++) {
        int row = wm * 64 + i * 16 + l16;
        aoff[i] = row * 32 + ((quad ^ ((row >> 1) & 3)) * 8);
    }
    #pragma unroll
    for (int j = 0; j < 4; j++) {
        int row = wn * 64 + j * 16 + l16;
        boff[j] = row * 32 + ((quad ^ ((row >> 1) & 3)) * 8);
    }

    // prologue: stage tiles 0,1; gate tile 0 (tile 1 stays in flight)
    stageA(0); stageB(0); stageA(1); stageB(1);
    VMCNT(4);
    __builtin_amdgcn_s_barrier();
    __builtin_amdgcn_sched_barrier(0);

    floatx4 acc[4][4] = {};

    for (int t = 0; t < NT; t++) {
        const __bf16* Ab = lds + (t % 3) * ASLOT;
        const __bf16* Bb = lds + 3 * ASLOT + (t % 3) * ASLOT;

        if (t) {   // gate: tile t landed; tile t+1 (if issued) stays in flight
            if (t + 1 < NT) { VMCNT(4); } else { VMCNT(0); }
            __builtin_amdgcn_s_barrier();
            __builtin_amdgcn_sched_barrier(0);
        }
        bool pre = (t + 2 < NT);
        bf16x8 ar[2], br[4];

        // ---- phase A: m-half 0 ----
        if (pre) stageA(t + 2);
        #pragma unroll
        for (int j = 0; j < 4; j++)
            br[j] = *(const bf16x8*)&Bb[boff[j]];
        #pragma unroll
        for (int i = 0; i < 2; i++)
            ar[i] = *(const bf16x8*)&Ab[aoff[i]];
        __builtin_amdgcn_s_setprio(1);
        #pragma unroll
        for (int i = 0; i < 2; i++)
            #pragma unroll
            for (int j = 0; j < 4; j++)
                acc[i][j] = __builtin_amdgcn_mfma_f32_16x16x32_bf16(
                    ar[i], br[j], acc[i][j], 0, 0, 0);
        __builtin_amdgcn_s_setprio(0);
        __builtin_amdgcn_sched_barrier(0);

        // ---- phase B: m-half 1 (br register-cached) ----
        if (pre) stageB(t + 2);
        #pragma unroll
        for (int i = 0; i < 2; i++)
            ar[i] = *(const bf16x8*)&Ab[aoff[2 + i]];
        __builtin_amdgcn_s_setprio(1);
        #pragma unroll
        for (int i = 0; i < 2; i++)
            #pragma unroll
            for (int j = 0; j < 4; j++)
                acc[2 + i][j] = __builtin_amdgcn_mfma_f32_16x16x32_bf16(
                    ar[i], br[j], acc[2 + i][j], 0, 0, 0);
        __builtin_amdgcn_s_setprio(0);
        __builtin_amdgcn_sched_barrier(0);
    }

    // epilogue: col = l16 side, row = quad*4 + reg (16x16x32 C/D mapping)
    #pragma unroll
    for (int i = 0; i < 4; i++) {
        #pragma unroll
        for (int j = 0; j < 4; j++) {
            int col = n0 + wn * 64 + j * 16 + l16;
            float bv = bias ? bias[col] : 0.0f;
            #pragma unroll
            for (int r = 0; r < 4; r++) {
                int row = m0 + wm * 64 + i * 16 + quad * 4 + r;
                size_t idx = (size_t)row * Ndim + col;
                float v = acc[i][j][r] + bv;
                if (resF)    v += resF[idx];
                if (resB)    v += (float)resB[idx];
                if (do_relu) v  = fmaxf(v, 0.0f);
                if (outF) outF[idx] = v;
                if (outB) outB[idx] = (__bf16)v;
            }
        }
    }
}

// ---------------------------------------------------------------------------
// Fused q-projection + persistent attention (verified).
// Block = 128 rows x 2 heads.
// ---------------------------------------------------------------------------
constexpr int QLD = 136;
constexpr int KLD = 72;

__global__ __launch_bounds__(256) void mc_qattn(
    const __bf16* __restrict__ A,      // normb [M,H]
    const __bf16* __restrict__ Bt,     // Wqt [H,H]
    const float* __restrict__ bq,
    const float* __restrict__ pv,
    __bf16* __restrict__ attn)
{
    __shared__ __bf16 Qs[128 * QLD];
    __shared__ union {
        struct { __bf16 As[128 * 64]; __bf16 Bs[128 * 64]; } g;
        struct { __bf16 Ks[64 * KLD]; __bf16 KTs[64 * KLD];
                 __bf16 Ps[128 * KLD]; } a;
    } u;

    int tid  = threadIdx.x;
    int lane = tid & 63;
    int w    = tid >> 6;
    int l16  = lane & 15;
    int quad = lane >> 4;
    int sw   = l16 & 7;

    int hp = blockIdx.x;
    int m0 = blockIdx.y * 128;
    int n0 = hp * 128;

    int wm = (w >> 1) * 64, wn = (w & 1) * 64;
    floatx4 acc[4][4] = {};
    for (int k0 = 0; k0 < H; k0 += 64) {
        #pragma unroll
        for (int t = 0; t < 4; t++) {
            int f = t * 256 + tid;
            int r = f >> 3, c = (f & 7) ^ (r & 7);
            __builtin_amdgcn_global_load_lds(
                (const AS1 void*)(A + (size_t)(m0 + r) * H + k0 + c * 8),
                (AS3 void*)(u.g.As + f * 8), 16, 0, 0);
        }
        #pragma unroll
        for (int t = 0; t < 4; t++) {
            int f = t * 256 + tid;
            int r = f >> 3, c = (f & 7) ^ (r & 7);
            __builtin_amdgcn_global_load_lds(
                (const AS1 void*)(Bt + (size_t)(n0 + r) * H + k0 + c * 8),
                (AS3 void*)(u.g.Bs + f * 8), 16, 0, 0);
        }
        __syncthreads();
        #pragma unroll
        for (int ks = 0; ks < 2; ks++) {
            int cq = ((ks << 2) | quad) ^ sw;
            bf16x8 af[4], bfr[4];
            #pragma unroll
            for (int i = 0; i < 4; i++)
                af[i] = *(const bf16x8*)&u.g.As[(wm + i * 16 + l16) * 64 + cq * 8];
            #pragma unroll
            for (int j = 0; j < 4; j++)
                bfr[j] = *(const bf16x8*)&u.g.Bs[(wn + j * 16 + l16) * 64 + cq * 8];
            #pragma unroll
            for (int i = 0; i < 4; i++)
                #pragma unroll
                for (int j = 0; j < 4; j++)
                    acc[i][j] = __builtin_amdgcn_mfma_f32_16x16x32_bf16(
                        af[i], bfr[j], acc[i][j], 0, 0, 0);
        }
        __syncthreads();
    }

    #pragma unroll
    for (int i = 0; i < 4; i++) {
        #pragma unroll
        for (int j = 0; j < 4; j++) {
            int col = wn + j * 16 + l16;
            float bv = bq[n0 + col];
            #pragma unroll
            for (int r = 0; r < 4; r++) {
                int row = wm + i * 16 + quad * 4 + r;
                Qs[row * QLD + col] = (__bf16)(acc[i][j][r] + bv);
            }
        }
    }

    int rbase = w * 32;
    #pragma unroll
    for (int hh = 0; hh < 2; hh++) {
        int gh = 2 * hp + hh;
        __syncthreads();
        for (int i = tid; i < 64 * 64; i += 256) {
            int p = i >> 6, d = i & 63;
            __bf16 bv = (__bf16)pv[(size_t)p * H + gh * 64 + d];
            u.a.Ks[p * KLD + d]  = bv;
            u.a.KTs[d * KLD + p] = bv;
        }
        __syncthreads();

        floatx4 sc[2][4] = {};
        #pragma unroll
        for (int ks = 0; ks < 2; ks++) {
            bf16x8 aq[2], bk[4];
            #pragma unroll
            for (int i = 0; i < 2; i++)
                aq[i] = *(const bf16x8*)&Qs[(rbase + i * 16 + l16) * QLD +
                                            hh * 64 + ks * 32 + quad * 8];
            #pragma unroll
            for (int j = 0; j < 4; j++)
                bk[j] = *(const bf16x8*)&u.a.Ks[(j * 16 + l16) * KLD + ks * 32 + quad * 8];
            #pragma unroll
            for (int i = 0; i < 2; i++)
                #pragma unroll
                for (int j = 0; j < 4; j++)
                    sc[i][j] = __builtin_amdgcn_mfma_f32_16x16x32_bf16(
                        aq[i], bk[j], sc[i][j], 0, 0, 0);
        }

        #pragma unroll
        for (int i = 0; i < 2; i++) {
            #pragma unroll
            for (int r = 0; r < 4; r++) {
                float v0 = sc[i][0][r] * 0.125f;
                float v1 = sc[i][1][r] * 0.125f;
                float v2 = sc[i][2][r] * 0.125f;
                float v3 = sc[i][3][r] * 0.125f;
                float mx = fmaxf(fmaxf(v0, v1), fmaxf(v2, v3));
                #pragma unroll
                for (int off = 8; off > 0; off >>= 1) mx = fmaxf(mx, __shfl_xor(mx, off));
                float e0 = __expf(v0 - mx), e1 = __expf(v1 - mx);
                float e2 = __expf(v2 - mx), e3 = __expf(v3 - mx);
                float sm = e0 + e1 + e2 + e3;
                #pragma unroll
                for (int off = 8; off > 0; off >>= 1) sm += __shfl_xor(sm, off);
                float inv = __frcp_rn(sm);
                int row = rbase + i * 16 + quad * 4 + r;
                u.a.Ps[row * KLD +  0 + l16] = (__bf16)(e0 * inv);
                u.a.Ps[row * KLD + 16 + l16] = (__bf16)(e1 * inv);
                u.a.Ps[row * KLD + 32 + l16] = (__bf16)(e2 * inv);
                u.a.Ps[row * KLD + 48 + l16] = (__bf16)(e3 * inv);
            }
        }
        __syncthreads();

        floatx4 ov[2][4] = {};
        #pragma unroll
        for (int ks = 0; ks < 2; ks++) {
            bf16x8 ap[2], bkt[4];
            #pragma unroll
            for (int i = 0; i < 2; i++)
                ap[i] = *(const bf16x8*)&u.a.Ps[(rbase + i * 16 + l16) * KLD + ks * 32 + quad * 8];
            #pragma unroll
            for (int j = 0; j < 4; j++)
                bkt[j] = *(const bf16x8*)&u.a.KTs[(j * 16 + l16) * KLD + ks * 32 + quad * 8];
            #pragma unroll
            for (int i = 0; i < 2; i++)
                #pragma unroll
                for (int j = 0; j < 4; j++)
                    ov[i][j] = __builtin_amdgcn_mfma_f32_16x16x32_bf16(
                        ap[i], bkt[j], ov[i][j], 0, 0, 0);
        }

        #pragma unroll
        for (int i = 0; i < 2; i++) {
            #pragma unroll
            for (int j = 0; j < 4; j++) {
                int col = j * 16 + l16;
                #pragma unroll
                for (int r = 0; r < 4; r++) {
                    int row = rbase + i * 16 + quad * 4 + r;
                    attn[(size_t)(m0 + row) * H + gh * 64 + col] = (__bf16)ov[i][j][r];
                }
            }
        }
    }
}

// ---------------------------------------------------------------------------
extern "C" void kernel_launch(void* const* d_in, const int* in_sizes, int n_in,
                              void* d_out, int out_size, void* d_ws, size_t ws_size,
                              hipStream_t stream)
{
    const float* hidden = (const float*)d_in[0];
    const float* pv   = (const float*)d_in[3];
    const float* Wq   = (const float*)d_in[4];
    const float* bq   = (const float*)d_in[5];
    const float* Wo   = (const float*)d_in[6];
    const float* bo   = (const float*)d_in[7];
    const float* ln_g = (const float*)d_in[8];
    const float* ln_b = (const float*)d_in[9];
    const float* W1   = (const float*)d_in[10];
    const float* b1   = (const float*)d_in[11];
    const float* W2   = (const float*)d_in[12];
    const float* b2   = (const float*)d_in[13];
    const float* mW1  = (const float*)d_in[14];
    const float* mb1  = (const float*)d_in[15];
    const float* mW2  = (const float*)d_in[16];
    const float* mb2  = (const float*)d_in[17];

    float* out = (float*)d_out;
    char*  wsb = (char*)d_ws;

    constexpr size_t MB = 1024 * 1024;
    __bf16* normb  = (__bf16*)(wsb);               // 16 MB  [M,H]
    __bf16* attnb  = (__bf16*)(wsb + 16  * MB);    // 16 MB  [M,H]
    __bf16* out1b  = (__bf16*)(wsb + 32  * MB);    // 16 MB  [M,H]
    __bf16* hb     = (__bf16*)(wsb + 48  * MB);    // 32 MB  [M,INTER]
    __bf16* Wqt    = (__bf16*)(wsb + 80  * MB);    // 2 MB   [H,H]
    __bf16* Wot    = (__bf16*)(wsb + 82  * MB);    // 2 MB   [H,H]
    __bf16* W1t    = (__bf16*)(wsb + 84  * MB);    // 4 MB   [INTER,H]
    __bf16* W2t    = (__bf16*)(wsb + 88  * MB);    // 4 MB   [H,INTER]
    float*  nb1    = (float*) (wsb + 92  * MB);    // 8 KB
    float*  nb2    = (float*) (wsb + 92  * MB + 8192);

    // 0) fused weight prep (4 transposes + momentum + bias updates)
    mc_prep<<<6156, 256, 0, stream>>>(Wq, Wo, W1, mW1, W2, mW2,
                                      Wqt, Wot, W1t, W2t,
                                      b1, mb1, nb1, b2, mb2, nb2);

    // 1) hs_norm = LN(hidden) -> bf16
    mc_ln_kernel<<<M, 256, 0, stream>>>(hidden, ln_g, ln_b, normb);

    // 2+3) fused q-projection + attention -> attnb
    mc_qattn<<<dim3(NH / 2, M / 128), 256, 0, stream>>>(normb, Wqt, bq, pv, attnb);

    // 4) out1 = hidden + attnb @ Wo + bo -> bf16 out1b  (N=1024,K=1024; 512 wg)
    mc_gemm_t<<<(H / 128) * (M / 128), 256, 0, stream>>>(
        attnb, Wot, bo, hidden, nullptr, nullptr, out1b, H, H, 0);

    // 5) h = relu(out1b @ W1t^T + nb1) -> bf16          (N=2048,K=1024; 1024 wg)
    mc_gemm_t<<<(INTER / 128) * (M / 128), 256, 0, stream>>>(
        out1b, W1t, nb1, nullptr, nullptr, nullptr, hb, INTER, H, 1);

    // 6) out = out1b + hb @ W2t^T + nb2 -> fp32 d_out   (N=1024,K=2048; 512 wg)
    mc_gemm_t<<<(H / 128) * (M / 128), 256, 0, stream>>>(
        hb, W2t, nb2, nullptr, out1b, out, nullptr, H, INTER, 0);
}